// Round 11
// baseline (309.629 us; speedup 1.0000x reference)
//
#include <hip/hip_runtime.h>
#include <hip/hip_bf16.h>
#include <math.h>

#define SEQ 2048
#define DMODEL 1024
#define QH 16
#define KVH 4
#define DH 64
#define TOPK 64
#define KV_D (KVH * DH)   // 256
#define CAP 128
#define CCAP 256          // candidate values capacity (values-only, 1 KB in own S row)
#define SROW 1028         // padded S row stride (floats), half-seq chunk + 4

typedef __attribute__((ext_vector_type(8))) short short8;
typedef __attribute__((ext_vector_type(4))) float floatx4;

// ---------------- monotone float<->uint mapping ----------------
__device__ __forceinline__ unsigned f2u(float f) {
    unsigned u = __float_as_uint(f);
    return (u & 0x80000000u) ? ~u : (u | 0x80000000u);
}
__device__ __forceinline__ float u2f(unsigned u) {
    unsigned v = (u & 0x80000000u) ? (u & 0x7fffffffu) : ~u;
    return __uint_as_float(v);
}
__device__ __forceinline__ unsigned short f2bf(float x) {   // RNE f32->bf16
    unsigned u = __float_as_uint(x);
    return (unsigned short)((u + 0x7fffu + ((u >> 16) & 1u)) >> 16);
}
__device__ __forceinline__ float bf2f(unsigned short h) {
    return __uint_as_float((unsigned)h << 16);
}
__device__ __forceinline__ void split4(float4 f, ushort4& h, ushort4& l) {
    h.x = f2bf(f.x); l.x = f2bf(f.x - bf2f(h.x));
    h.y = f2bf(f.y); l.y = f2bf(f.y - bf2f(h.y));
    h.z = f2bf(f.z); l.z = f2bf(f.z - bf2f(h.z));
    h.w = f2bf(f.w); l.w = f2bf(f.w - bf2f(h.w));
}

// ---------------- fused converts + RoPE LUT in one launch ----------------
__global__ __launch_bounds__(256) void cvt_all(const float* __restrict__ x,
                                               const float* __restrict__ Wq,
                                               const float* __restrict__ Wk,
                                               const float* __restrict__ Wv,
                                               const float* __restrict__ Wo,
                                               unsigned short* __restrict__ xhi,
                                               unsigned short* __restrict__ xlo,
                                               unsigned short* __restrict__ wbhi,
                                               unsigned short* __restrict__ wblo,
                                               unsigned short* __restrict__ wo,
                                               float* __restrict__ cosT,
                                               float* __restrict__ sinT) {
    int idx = blockIdx.x * 256 + threadIdx.x;
    if (idx >= 1196032) return;
    float4 f;
    ushort4 h, l;
    if (idx < 524288) {                       // x split
        f = ((const float4*)x)[idx];
        split4(f, h, l);
        ((ushort4*)xhi)[idx] = h;
        ((ushort4*)xlo)[idx] = l;
    } else if (idx < 786432) {                // Wq -> wb rows 0..1023
        int s = idx - 524288;
        f = ((const float4*)Wq)[s];
        split4(f, h, l);
        ((ushort4*)wbhi)[s] = h;
        ((ushort4*)wblo)[s] = l;
    } else if (idx < 851968) {                // Wk -> wb rows 1024..1279
        int s = idx - 786432;
        f = ((const float4*)Wk)[s];
        split4(f, h, l);
        ((ushort4*)wbhi)[idx - 524288] = h;
        ((ushort4*)wblo)[idx - 524288] = l;
    } else if (idx < 917504) {                // Wv -> wb rows 1280..1535
        int s = idx - 851968;
        f = ((const float4*)Wv)[s];
        split4(f, h, l);
        ((ushort4*)wbhi)[idx - 524288] = h;
        ((ushort4*)wblo)[idx - 524288] = l;
    } else if (idx < 1179648) {               // Wo single bf16
        int s = idx - 917504;
        f = ((const float4*)Wo)[s];
        ushort4 o;
        o.x = f2bf(f.x); o.y = f2bf(f.y); o.z = f2bf(f.z); o.w = f2bf(f.w);
        ((ushort4*)wo)[s] = o;
    } else {                                   // RoPE cos/sin LUT, 4 entries/thread
        int s = idx - 1179648;                 // 0..16383
        int e0 = s * 4;
        float ft = (float)(e0 >> 5);
        int d0 = e0 & 31;
        float4 cw, sw;
#pragma unroll
        for (int k = 0; k < 4; ++k) {
            float inv = powf(10000.0f, -(float)(d0 + k) * (1.0f / 32.0f));
            float ss, cc;
            sincosf(ft * inv, &ss, &cc);
            ((float*)&cw)[k] = cc;
            ((float*)&sw)[k] = ss;
        }
        ((float4*)cosT)[s] = cw;
        ((float4*)sinT)[s] = sw;
    }
}

// ---------------- async 16B global->LDS ----------------
__device__ __forceinline__ void async16(const void* g, void* l) {
    __builtin_amdgcn_global_load_lds(
        (const __attribute__((address_space(1))) unsigned int*)g,
        (__attribute__((address_space(3))) unsigned int*)l, 16, 0, 0);
}

// ---------------- fused QKV GEMM (split bf16, ~f32) + RoPE epilogue ----------------
// 64x128 tile -> 384 blocks. Wave = 32 rows x 64 cols (rope (d,d+32) in-lane).
__global__ __launch_bounds__(256, 2) void gemm_qkv(const unsigned short* __restrict__ Ah,
                                                   const unsigned short* __restrict__ Al,
                                                   const unsigned short* __restrict__ Bh,
                                                   const unsigned short* __restrict__ Bl,
                                                   const float* __restrict__ cosT,
                                                   const float* __restrict__ sinT,
                                                   unsigned short* __restrict__ qhi,
                                                   unsigned short* __restrict__ qlo,
                                                   unsigned short* __restrict__ khi,
                                                   unsigned short* __restrict__ klo,
                                                   float* __restrict__ vv) {
    const int K = DMODEL;
    __shared__ unsigned short lAh[64 * 32];
    __shared__ unsigned short lAl[64 * 32];
    __shared__ unsigned short lBh[128 * 32];
    __shared__ unsigned short lBl[128 * 32];
    const int tid = threadIdx.x;
    const int lane = tid & 63;
    const int wid = tid >> 6;
    const int m0 = blockIdx.y * 64, n0 = blockIdx.x * 128;
    const int mh = (wid >> 1) * 32;             // wave row-half
    const int nh = (wid & 1) * 64;              // wave col-half (64 contiguous cols)
    const bool isv = (n0 >= 1280);

    floatx4 acc[2][4];
#pragma unroll
    for (int a = 0; a < 2; ++a)
#pragma unroll
        for (int b = 0; b < 4; ++b) acc[a][b] = (floatx4){0.f, 0.f, 0.f, 0.f};

    const int srow = tid >> 2;                  // 0..63
    const int skb = (tid & 3) ^ ((tid >> 3) & 3);
    const unsigned short* pAh = Ah + (size_t)(m0 + srow) * K + skb * 8;
    const unsigned short* pAl = Al + (size_t)(m0 + srow) * K + skb * 8;
    const unsigned short* pBh = Bh + (size_t)(n0 + srow) * K + skb * 8;
    const unsigned short* pBl = Bl + (size_t)(n0 + srow) * K + skb * 8;
    unsigned lbase = __builtin_amdgcn_readfirstlane((unsigned)(wid * 1024));

    for (int k0 = 0; k0 < K; k0 += 32) {
        async16(pAh + k0, (char*)lAh + lbase);
        async16(pBh + k0, (char*)lBh + lbase);
        async16(pBh + (size_t)64 * K + k0, (char*)lBh + lbase + 4096);
        if (!isv) {
            async16(pAl + k0, (char*)lAl + lbase);
            async16(pBl + k0, (char*)lBl + lbase);
            async16(pBl + (size_t)64 * K + k0, (char*)lBl + lbase + 4096);
        }
        __syncthreads();

        short8 ah[2], al[2], bh[4], bl[4];
#pragma unroll
        for (int mt = 0; mt < 2; ++mt) {
            int row = mh + mt * 16 + (lane & 15);
            int s = ((lane >> 4) ^ ((row >> 1) & 3)) * 8;
            ah[mt] = *(const short8*)&lAh[row * 32 + s];
            if (!isv) al[mt] = *(const short8*)&lAl[row * 32 + s];
        }
#pragma unroll
        for (int nt = 0; nt < 4; ++nt) {
            int row = nh + nt * 16 + (lane & 15);
            int s = ((lane >> 4) ^ ((row >> 1) & 3)) * 8;
            bh[nt] = *(const short8*)&lBh[row * 32 + s];
            if (!isv) bl[nt] = *(const short8*)&lBl[row * 32 + s];
        }
        if (isv) {
#pragma unroll
            for (int mt = 0; mt < 2; ++mt)
#pragma unroll
                for (int nt = 0; nt < 4; ++nt)
                    acc[mt][nt] = __builtin_amdgcn_mfma_f32_16x16x32_bf16(ah[mt], bh[nt], acc[mt][nt], 0, 0, 0);
        } else {
#pragma unroll
            for (int mt = 0; mt < 2; ++mt)
#pragma unroll
                for (int nt = 0; nt < 4; ++nt) {
                    floatx4 a = acc[mt][nt];
                    a = __builtin_amdgcn_mfma_f32_16x16x32_bf16(al[mt], bh[nt], a, 0, 0, 0);
                    a = __builtin_amdgcn_mfma_f32_16x16x32_bf16(ah[mt], bl[nt], a, 0, 0, 0);
                    a = __builtin_amdgcn_mfma_f32_16x16x32_bf16(ah[mt], bh[nt], a, 0, 0, 0);
                    acc[mt][nt] = a;
                }
        }
        __syncthreads();
    }

    // ---- epilogue ----
    const int cb = n0 + nh;                      // wave's 64-col base
    if (!isv) {
        const bool isq = (cb < 1024);
        const float qsc = isq ? 0.125f : 1.0f;   // fold 1/sqrt(64) into q exactly
#pragma unroll
        for (int mt = 0; mt < 2; ++mt)
#pragma unroll
            for (int nt = 0; nt < 2; ++nt) {
                const int d32 = nt * 16 + (lane & 15);
#pragma unroll
                for (int rr = 0; rr < 4; ++rr) {
                    int row = m0 + mh + mt * 16 + (lane >> 4) * 4 + rr;
                    float lo = acc[mt][nt][rr], hi = acc[mt][nt + 2][rr];
                    float c = cosT[row * 32 + d32], s = sinT[row * 32 + d32];
                    float rlo = (lo * c - hi * s) * qsc;
                    float rhi = (hi * c + lo * s) * qsc;
                    unsigned short hlo = f2bf(rlo), hhi = f2bf(rhi);
                    unsigned short llo = f2bf(rlo - bf2f(hlo));
                    unsigned short lhi = f2bf(rhi - bf2f(hhi));
                    if (isq) {
                        size_t o = (size_t)row * DMODEL + cb + d32;
                        qhi[o] = hlo; qhi[o + 32] = hhi;
                        qlo[o] = llo; qlo[o + 32] = lhi;
                    } else {
                        int kvh = (cb - 1024) >> 6;
                        size_t o = ((size_t)kvh * SEQ + row) * DH + d32;
                        khi[o] = hlo; khi[o + 32] = hhi;
                        klo[o] = llo; klo[o + 32] = lhi;
                    }
                }
            }
    } else {
#pragma unroll
        for (int mt = 0; mt < 2; ++mt)
#pragma unroll
            for (int nt = 0; nt < 4; ++nt) {
                int vcol = cb + nt * 16 + (lane & 15) - 1280;
                int rbase = m0 + mh + mt * 16 + (lane >> 4) * 4;
#pragma unroll
                for (int rr = 0; rr < 4; ++rr)
                    vv[(size_t)(rbase + rr) * KV_D + vcol] = acc[mt][nt][rr];
            }
    }
}

// ---------------- Wo GEMM: 64x128 tile -> 256 blocks ----------------
__global__ __launch_bounds__(256, 2) void gemm_wo(const unsigned short* __restrict__ A,
                                                  const unsigned short* __restrict__ B,
                                                  float* __restrict__ C) {
    const int N = DMODEL, K = DMODEL;
    __shared__ unsigned short lAs[64 * 32];
    __shared__ unsigned short lBs[128 * 32];
    const int tid = threadIdx.x;
    const int lane = tid & 63;
    const int wid = tid >> 6;
    const int m0 = blockIdx.y * 64, n0 = blockIdx.x * 128;

    floatx4 acc[4][2];
#pragma unroll
    for (int a = 0; a < 4; ++a)
#pragma unroll
        for (int b = 0; b < 2; ++b) acc[a][b] = (floatx4){0.f, 0.f, 0.f, 0.f};

    const int srow = tid >> 2;
    const int skb = (tid & 3) ^ ((tid >> 3) & 3);
    const unsigned short* Ag = A + (size_t)(m0 + srow) * K + skb * 8;
    const unsigned short* Bg = B + (size_t)(n0 + srow) * K + skb * 8;
    unsigned lbase = __builtin_amdgcn_readfirstlane((unsigned)(wid * 1024));

    for (int k0 = 0; k0 < K; k0 += 32) {
        async16(Ag + k0, (char*)lAs + lbase);
        async16(Bg + k0, (char*)lBs + lbase);
        async16(Bg + (size_t)64 * K + k0, (char*)lBs + lbase + 4096);
        __syncthreads();

        short8 af[4], bf[2];
#pragma unroll
        for (int mt = 0; mt < 4; ++mt) {
            int row = mt * 16 + (lane & 15);
            int s = ((lane >> 4) ^ ((row >> 1) & 3)) * 8;
            af[mt] = *(const short8*)&lAs[row * 32 + s];
        }
#pragma unroll
        for (int nt = 0; nt < 2; ++nt) {
            int row = wid * 32 + nt * 16 + (lane & 15);
            int s = ((lane >> 4) ^ ((row >> 1) & 3)) * 8;
            bf[nt] = *(const short8*)&lBs[row * 32 + s];
        }
#pragma unroll
        for (int mt = 0; mt < 4; ++mt)
#pragma unroll
            for (int nt = 0; nt < 2; ++nt)
                acc[mt][nt] = __builtin_amdgcn_mfma_f32_16x16x32_bf16(af[mt], bf[nt], acc[mt][nt], 0, 0, 0);
        __syncthreads();
    }
#pragma unroll
    for (int mt = 0; mt < 4; ++mt)
#pragma unroll
        for (int nt = 0; nt < 2; ++nt) {
            int col = n0 + wid * 32 + nt * 16 + (lane & 15);
            int rbase = m0 + mt * 16 + (lane >> 4) * 4;
#pragma unroll
            for (int rr = 0; rr < 4; ++rr)
                C[(size_t)(rbase + rr) * N + col] = acc[mt][nt][rr];
        }
}

// ---------------- AV fallback helper ----------------
__device__ __forceinline__ void av_group(float w, int jbase, const float* __restrict__ vb,
                                         float& acc) {
    unsigned long long mk = __ballot(w > 0.f);
    while (mk) {
        int l = __ffsll((unsigned long long)mk) - 1;
        mk &= mk - 1;
        float wj = __shfl(w, l, 64);
        acc += wj * vb[(size_t)(jbase + l * 4) * KV_D];
    }
}

// ---------------- phase-A score slice: strided j-blocks over a 1024-col chunk ----------------
__device__ __forceinline__ void score_chunk(const unsigned short* __restrict__ khi,
                                            const unsigned short* __restrict__ klo,
                                            float* __restrict__ S,
                                            const short8& ah0, const short8& ah1,
                                            const short8& al0, const short8& al1,
                                            int kvh, int w, int lane, int imax, int cbase) {
    const int koff = (lane >> 4) * 8;
#pragma unroll
    for (int n = 0; n < 4; ++n) {
        int jbi = cbase + w + n * 16;
        int jb = jbi * 16;
        if (jb <= imax) {
            size_t bidx = ((size_t)kvh * SEQ + jb + (lane & 15)) * DH + koff;
            short8 bh0 = *(const short8*)(khi + bidx);
            short8 bh1 = *(const short8*)(khi + bidx + 32);
            short8 bl0 = *(const short8*)(klo + bidx);
            short8 bl1 = *(const short8*)(klo + bidx + 32);
            floatx4 acc = (floatx4){0.f, 0.f, 0.f, 0.f};
            acc = __builtin_amdgcn_mfma_f32_16x16x32_bf16(al0, bh0, acc, 0, 0, 0);
            acc = __builtin_amdgcn_mfma_f32_16x16x32_bf16(al1, bh1, acc, 0, 0, 0);
            acc = __builtin_amdgcn_mfma_f32_16x16x32_bf16(ah0, bl0, acc, 0, 0, 0);
            acc = __builtin_amdgcn_mfma_f32_16x16x32_bf16(ah1, bl1, acc, 0, 0, 0);
            acc = __builtin_amdgcn_mfma_f32_16x16x32_bf16(ah0, bh0, acc, 0, 0, 0);
            acc = __builtin_amdgcn_mfma_f32_16x16x32_bf16(ah1, bh1, acc, 0, 0, 0);
            int col = (jb & 1023) + (lane & 15);
            int rbase = (lane >> 4) * 4;
#pragma unroll
            for (int rr = 0; rr < 4; ++rr)
                S[(size_t)(rbase + rr) * SROW + col] = acc[rr];   // q pre-scaled by 1/8
        }
    }
}

// ---------------- attention: block = (head, 16 q-rows), 16 waves, 2 blocks/CU ----------------
__global__ __launch_bounds__(1024, 8) void attn_block(const unsigned short* __restrict__ qhi,
                                                      const unsigned short* __restrict__ qlo,
                                                      const unsigned short* __restrict__ khi,
                                                      const unsigned short* __restrict__ klo,
                                                      const float* __restrict__ v,
                                                      unsigned short* __restrict__ outb) {
    extern __shared__ float S[];                 // [16][SROW] f32; own row reused as scratch
    const int lane = threadIdx.x & 63;
    const int w = threadIdx.x >> 6;              // 0..15
    const int t = 127 - blockIdx.x;              // longest tiles first
    const int h = blockIdx.y;
    const int kvh = h >> 2;
    const int m0 = t * 16;
    const int imax = m0 + 15;

    // A-fragments (q rows m0..m0+15)
    const int arow = m0 + (lane & 15);
    const int koff = (lane >> 4) * 8;
    size_t aidx = (size_t)arow * DMODEL + h * DH + koff;
    short8 ah0 = *(const short8*)(qhi + aidx);
    short8 ah1 = *(const short8*)(qhi + aidx + 32);
    short8 al0 = *(const short8*)(qlo + aidx);
    short8 al1 = *(const short8*)(qlo + aidx + 32);

    const int irow = m0 + w;
    const int cmax = (irow >> 8) + 1;
    float* Srow = S + (size_t)w * SROW;
    uint4 uv[8];
#pragma unroll
    for (int c = 0; c < 8; ++c) uv[c] = make_uint4(0u, 0u, 0u, 0u);

    // ---- chunk 0: cols [0,1024) ----
    score_chunk(khi, klo, S, ah0, ah1, al0, al1, kvh, w, lane, imax, 0);
    __syncthreads();
#pragma unroll
    for (int c = 0; c < 4; ++c) {
        if (c < cmax) {
            const int j0 = c * 256 + lane * 4;
            float4 f = *(const float4*)&Srow[j0];
            uv[c].x = (j0 + 0 <= irow) ? f2u(f.x) : 0u;
            uv[c].y = (j0 + 1 <= irow) ? f2u(f.y) : 0u;
            uv[c].z = (j0 + 2 <= irow) ? f2u(f.z) : 0u;
            uv[c].w = (j0 + 3 <= irow) ? f2u(f.w) : 0u;
        }
    }
    __syncthreads();

    // ---- chunk 1: cols [1024,2048) ----
    if (imax >= 1024) {
        score_chunk(khi, klo, S, ah0, ah1, al0, al1, kvh, w, lane, imax, 64);
    }
    __syncthreads();
#pragma unroll
    for (int c = 4; c < 8; ++c) {
        if (c < cmax) {
            const int j0 = (c - 4) * 256 + lane * 4;
            float4 f = *(const float4*)&Srow[j0];
            int jg = c * 256 + lane * 4;
            uv[c].x = (jg + 0 <= irow) ? f2u(f.x) : 0u;
            uv[c].y = (jg + 1 <= irow) ? f2u(f.y) : 0u;
            uv[c].z = (jg + 2 <= irow) ? f2u(f.z) : 0u;
            uv[c].w = (jg + 3 <= irow) ? f2u(f.w) : 0u;
        }
    }
    // no barrier needed: from here each wave only touches its OWN Srow.

    // per-lane max, then wave max (um) and wave min-of-lane-max (Lb)
    unsigned lmax = 0u;
#pragma unroll
    for (int c = 0; c < 8; ++c)
        lmax = max(lmax, max(max(uv[c].x, uv[c].y), max(uv[c].z, uv[c].w)));
    unsigned um = lmax, Lb = lmax;
#pragma unroll
    for (int o = 32; o > 0; o >>= 1) {
        um = max(um, (unsigned)__shfl_xor((int)um, o, 64));
        Lb = min(Lb, (unsigned)__shfl_xor((int)Lb, o, 64));
    }
    const float mf = u2f(um);
    const unsigned long long lmask = (lane == 0) ? 0ull : (~0ull >> (64 - lane));

    // ---- exact 64th-largest: max p with count(u >= p) >= 64 ----
    // Candidate pre-filter (values only): the 64 lane-maxima are all >= Lb, so the
    // 64th largest is >= Lb and counting over {u >= Lb} is decision-equivalent.
    unsigned p = 1u;
    if (irow >= TOPK) {
        unsigned diff = Lb ^ um;
        if (diff == 0u) {
            p = um;
        } else {
            const int hb = 31 - __builtin_clz(diff);
            const unsigned pre = (hb >= 31) ? 0u : ((um >> (hb + 1)) << (hb + 1));
            const unsigned thr0 = Lb ? Lb : 1u;      // valid u >= 1; invalid u == 0
            unsigned* cand = (unsigned*)Srow;        // 256 x 4B in own row
            int nc = 0;
#pragma unroll
            for (int c = 0; c < 8; ++c) {
                if (c < cmax) {
#pragma unroll
                    for (int e = 0; e < 4; ++e) {
                        unsigned u = (e == 0) ? uv[c].x : (e == 1) ? uv[c].y
                                   : (e == 2) ? uv[c].z : uv[c].w;
                        bool kp = (u >= thr0);
                        unsigned long long mk = __ballot(kp);
                        if (kp) {
                            int pos = nc + __popcll(mk & lmask);
                            if (pos < CCAP) cand[pos] = u;
                        }
                        nc += (int)__popcll(mk);
                    }
                }
            }
            p = pre;
            if (nc <= CCAP) {
                // search over <=4 candidate slots/lane
                unsigned cu0 = cand[lane];
                unsigned cu1 = cand[64 + lane];
                unsigned cu2 = cand[128 + lane];
                unsigned cu3 = cand[192 + lane];
                cu0 = (lane < nc) ? cu0 : 0u;
                cu1 = (64 + lane < nc) ? cu1 : 0u;
                cu2 = (128 + lane < nc) ? cu2 : 0u;
                cu3 = (192 + lane < nc) ? cu3 : 0u;
                for (int b = hb; b >= 0; --b) {
                    unsigned cv = p | (1u << b);
                    int cnt = __popcll(__ballot(cu0 >= cv));
                    cnt += __popcll(__ballot(cu1 >= cv));
                    cnt += __popcll(__ballot(cu2 >= cv));
                    cnt += __popcll(__ballot(cu3 >= cv));
                    if (cnt >= TOPK) p = cv;
                }
            } else {
                // rare: huge candidate set -> full search on uv
                for (int b = hb; b >= 0; --b) {
                    unsigned cv = p | (1u << b);
                    int cnt = 0;
#pragma unroll
                    for (int c = 0; c < 8; ++c) {
                        if (c < cmax) {
                            cnt += __popcll(__ballot(uv[c].x >= cv));
                            cnt += __popcll(__ballot(uv[c].y >= cv));
                            cnt += __popcll(__ballot(uv[c].z >= cv));
                            cnt += __popcll(__ballot(uv[c].w >= cv));
                        }
                    }
                    if (cnt >= TOPK) p = cv;
                }
            }
        }
    }

    // compact kept (w, j) pairs into own S row (overwrites cand; search is done)
    float2* pl = (float2*)Srow;
    int base = 0;
#pragma unroll
    for (int c = 0; c < 8; ++c) {
        if (c < cmax) {
#pragma unroll
            for (int e = 0; e < 4; ++e) {
                unsigned u = (e == 0) ? uv[c].x : (e == 1) ? uv[c].y : (e == 2) ? uv[c].z : uv[c].w;
                bool kp = (u >= p);
                unsigned long long mk = __ballot(kp);
                if (kp) {
                    int pos = base + __popcll(mk & lmask);
                    if (pos < CAP)
                        pl[pos] = make_float2(__expf(u2f(u) - mf),
                                              __int_as_float(c * 256 + lane * 4 + e));
                }
                base += (int)__popcll(mk);
            }
        }
    }

    const float* vb = v + kvh * DH + lane;
    float acc = 0.f, den = 0.f;
    if (base <= CAP) {
        int l = 0;
        for (; l + 16 <= base; l += 16) {
            float2 pr[16];
            float vx[16];
#pragma unroll
            for (int u = 0; u < 16; ++u) pr[u] = pl[l + u];
#pragma unroll
            for (int u = 0; u < 16; ++u)
                vx[u] = vb[(size_t)__float_as_int(pr[u].y) * KV_D];
#pragma unroll
            for (int u = 0; u < 16; ++u) { den += pr[u].x; acc += pr[u].x * vx[u]; }
        }
        for (; l < base; ++l) {
            float2 pp = pl[l];
            den += pp.x;
            acc += pp.x * vb[(size_t)__float_as_int(pp.y) * KV_D];
        }
    } else {
        // fallback (massive ties): exact path from uv registers
        float lsum = 0.f;
#pragma unroll
        for (int c = 0; c < 8; ++c) {
            if (c < cmax) {
                float w0 = (uv[c].x >= p) ? __expf(u2f(uv[c].x) - mf) : 0.f;
                float w1 = (uv[c].y >= p) ? __expf(u2f(uv[c].y) - mf) : 0.f;
                float w2 = (uv[c].z >= p) ? __expf(u2f(uv[c].z) - mf) : 0.f;
                float w3 = (uv[c].w >= p) ? __expf(u2f(uv[c].w) - mf) : 0.f;
                lsum += (w0 + w1) + (w2 + w3);
                av_group(w0, c * 256 + 0, vb, acc);
                av_group(w1, c * 256 + 1, vb, acc);
                av_group(w2, c * 256 + 2, vb, acc);
                av_group(w3, c * 256 + 3, vb, acc);
            }
        }
        den = lsum;
#pragma unroll
        for (int o = 32; o > 0; o >>= 1) den += __shfl_xor(den, o, 64);
    }

    outb[(size_t)irow * DMODEL + h * DH + lane] = f2bf(acc / den);
}

extern "C" void kernel_launch(void* const* d_in, const int* in_sizes, int n_in,
                              void* d_out, int out_size, void* d_ws, size_t ws_size,
                              hipStream_t stream) {
    const float* x  = (const float*)d_in[0];
    const float* Wq = (const float*)d_in[1];
    const float* Wk = (const float*)d_in[2];
    const float* Wv = (const float*)d_in[3];
    const float* Wo = (const float*)d_in[4];
    float* out = (float*)d_out;

    float* ws = (float*)d_ws;
    float* vv   = ws;                               // 2048*256 f32
    float* cosT = vv + (size_t)SEQ * KV_D;          // 65536 f32
    float* sinT = cosT + SEQ * 32;                  // 65536 f32
    unsigned short* bfp = (unsigned short*)(sinT + SEQ * 32);
    unsigned short* xhi  = bfp;  bfp += (size_t)SEQ * DMODEL;      // 2M
    unsigned short* xlo  = bfp;  bfp += (size_t)SEQ * DMODEL;      // 2M
    unsigned short* wbhi = bfp;  bfp += (size_t)1536 * DMODEL;     // 1.5M
    unsigned short* wblo = bfp;  bfp += (size_t)1536 * DMODEL;     // 1.5M
    unsigned short* wob  = bfp;  bfp += (size_t)DMODEL * DMODEL;   // 1M
    unsigned short* qhi  = bfp;  bfp += (size_t)SEQ * DMODEL;      // 2M
    unsigned short* qlo  = bfp;  bfp += (size_t)SEQ * DMODEL;      // 2M
    unsigned short* khi  = bfp;  bfp += (size_t)KVH * SEQ * DH;    // 512K
    unsigned short* klo  = bfp;  bfp += (size_t)KVH * SEQ * DH;    // 512K
    unsigned short* attnb = xhi;   // xhi dead after QKV gemm

    dim3 blk(256);

    // converts + RoPE LUT (single launch)
    cvt_all<<<(1196032 + 255) / 256, blk, 0, stream>>>(x, Wq, Wk, Wv, Wo,
                                                       xhi, xlo, wbhi, wblo, wob,
                                                       cosT, sinT);

    // fused QKV projection + RoPE + layout (384 blocks)
    gemm_qkv<<<dim3(1536 / 128, SEQ / 64), blk, 0, stream>>>(xhi, xlo, wbhi, wblo,
                                                             cosT, sinT,
                                                             qhi, qlo, khi, klo, vv);

    // attention: 2 blocks/CU (S = 16 x 1028 floats = 65792 B)
    const int attn_lds = 16 * SROW * 4;
    hipFuncSetAttribute((const void*)attn_block,
                        hipFuncAttributeMaxDynamicSharedMemorySize, attn_lds);
    attn_block<<<dim3(SEQ / 16, QH), dim3(1024), attn_lds, stream>>>(qhi, qlo, khi, klo, vv, attnb);

    // output projection (256 blocks)
    gemm_wo<<<dim3(DMODEL / 128, SEQ / 64), blk, 0, stream>>>(attnb, wob, out);
}

// Round 12
// 306.085 us; speedup vs baseline: 1.0116x; 1.0116x over previous
//
#include <hip/hip_runtime.h>
#include <hip/hip_bf16.h>
#include <math.h>

#define SEQ 2048
#define DMODEL 1024
#define QH 16
#define KVH 4
#define DH 64
#define TOPK 64
#define KV_D (KVH * DH)   // 256
#define CAP 128
#define SROW 1028         // padded S row stride (floats), half-seq chunk + 4

typedef __attribute__((ext_vector_type(8))) short short8;
typedef __attribute__((ext_vector_type(4))) float floatx4;

// ---------------- monotone float<->uint mapping ----------------
__device__ __forceinline__ unsigned f2u(float f) {
    unsigned u = __float_as_uint(f);
    return (u & 0x80000000u) ? ~u : (u | 0x80000000u);
}
__device__ __forceinline__ float u2f(unsigned u) {
    unsigned v = (u & 0x80000000u) ? (u & 0x7fffffffu) : ~u;
    return __uint_as_float(v);
}
__device__ __forceinline__ unsigned short f2bf(float x) {   // RNE f32->bf16
    unsigned u = __float_as_uint(x);
    return (unsigned short)((u + 0x7fffu + ((u >> 16) & 1u)) >> 16);
}
__device__ __forceinline__ float bf2f(unsigned short h) {
    return __uint_as_float((unsigned)h << 16);
}
__device__ __forceinline__ void split4(float4 f, ushort4& h, ushort4& l) {
    h.x = f2bf(f.x); l.x = f2bf(f.x - bf2f(h.x));
    h.y = f2bf(f.y); l.y = f2bf(f.y - bf2f(h.y));
    h.z = f2bf(f.z); l.z = f2bf(f.z - bf2f(h.z));
    h.w = f2bf(f.w); l.w = f2bf(f.w - bf2f(h.w));
}

// ---------------- fused converts + RoPE LUT in one launch ----------------
__global__ __launch_bounds__(256) void cvt_all(const float* __restrict__ x,
                                               const float* __restrict__ Wq,
                                               const float* __restrict__ Wk,
                                               const float* __restrict__ Wv,
                                               const float* __restrict__ Wo,
                                               unsigned short* __restrict__ xhi,
                                               unsigned short* __restrict__ xlo,
                                               unsigned short* __restrict__ wbhi,
                                               unsigned short* __restrict__ wblo,
                                               unsigned short* __restrict__ wo,
                                               float* __restrict__ cosT,
                                               float* __restrict__ sinT) {
    int idx = blockIdx.x * 256 + threadIdx.x;
    if (idx >= 1196032) return;
    float4 f;
    ushort4 h, l;
    if (idx < 524288) {                       // x split
        f = ((const float4*)x)[idx];
        split4(f, h, l);
        ((ushort4*)xhi)[idx] = h;
        ((ushort4*)xlo)[idx] = l;
    } else if (idx < 786432) {                // Wq -> wb rows 0..1023
        int s = idx - 524288;
        f = ((const float4*)Wq)[s];
        split4(f, h, l);
        ((ushort4*)wbhi)[s] = h;
        ((ushort4*)wblo)[s] = l;
    } else if (idx < 851968) {                // Wk -> wb rows 1024..1279
        int s = idx - 786432;
        f = ((const float4*)Wk)[s];
        split4(f, h, l);
        ((ushort4*)wbhi)[idx - 524288] = h;
        ((ushort4*)wblo)[idx - 524288] = l;
    } else if (idx < 917504) {                // Wv -> wb rows 1280..1535
        int s = idx - 851968;
        f = ((const float4*)Wv)[s];
        split4(f, h, l);
        ((ushort4*)wbhi)[idx - 524288] = h;
        ((ushort4*)wblo)[idx - 524288] = l;
    } else if (idx < 1179648) {               // Wo single bf16
        int s = idx - 917504;
        f = ((const float4*)Wo)[s];
        ushort4 o;
        o.x = f2bf(f.x); o.y = f2bf(f.y); o.z = f2bf(f.z); o.w = f2bf(f.w);
        ((ushort4*)wo)[s] = o;
    } else {                                   // RoPE cos/sin LUT, 4 entries/thread
        int s = idx - 1179648;                 // 0..16383
        int e0 = s * 4;
        float ft = (float)(e0 >> 5);
        int d0 = e0 & 31;
        float4 cw, sw;
#pragma unroll
        for (int k = 0; k < 4; ++k) {
            float inv = powf(10000.0f, -(float)(d0 + k) * (1.0f / 32.0f));
            float ss, cc;
            sincosf(ft * inv, &ss, &cc);
            ((float*)&cw)[k] = cc;
            ((float*)&sw)[k] = ss;
        }
        ((float4*)cosT)[s] = cw;
        ((float4*)sinT)[s] = sw;
    }
}

// ---------------- async 16B global->LDS ----------------
__device__ __forceinline__ void async16(const void* g, void* l) {
    __builtin_amdgcn_global_load_lds(
        (const __attribute__((address_space(1))) unsigned int*)g,
        (__attribute__((address_space(3))) unsigned int*)l, 16, 0, 0);
}

// ---------------- fused QKV GEMM (split bf16, ~f32) + RoPE epilogue ----------------
// 64x128 tile -> 384 blocks. Wave = 32 rows x 64 cols (rope (d,d+32) in-lane).
__global__ __launch_bounds__(256, 2) void gemm_qkv(const unsigned short* __restrict__ Ah,
                                                   const unsigned short* __restrict__ Al,
                                                   const unsigned short* __restrict__ Bh,
                                                   const unsigned short* __restrict__ Bl,
                                                   const float* __restrict__ cosT,
                                                   const float* __restrict__ sinT,
                                                   unsigned short* __restrict__ qhi,
                                                   unsigned short* __restrict__ qlo,
                                                   unsigned short* __restrict__ khi,
                                                   unsigned short* __restrict__ klo,
                                                   float* __restrict__ vv) {
    const int K = DMODEL;
    __shared__ unsigned short lAh[64 * 32];
    __shared__ unsigned short lAl[64 * 32];
    __shared__ unsigned short lBh[128 * 32];
    __shared__ unsigned short lBl[128 * 32];
    const int tid = threadIdx.x;
    const int lane = tid & 63;
    const int wid = tid >> 6;
    const int m0 = blockIdx.y * 64, n0 = blockIdx.x * 128;
    const int mh = (wid >> 1) * 32;             // wave row-half
    const int nh = (wid & 1) * 64;              // wave col-half (64 contiguous cols)
    const bool isv = (n0 >= 1280);

    floatx4 acc[2][4];
#pragma unroll
    for (int a = 0; a < 2; ++a)
#pragma unroll
        for (int b = 0; b < 4; ++b) acc[a][b] = (floatx4){0.f, 0.f, 0.f, 0.f};

    const int srow = tid >> 2;                  // 0..63
    const int skb = (tid & 3) ^ ((tid >> 3) & 3);
    const unsigned short* pAh = Ah + (size_t)(m0 + srow) * K + skb * 8;
    const unsigned short* pAl = Al + (size_t)(m0 + srow) * K + skb * 8;
    const unsigned short* pBh = Bh + (size_t)(n0 + srow) * K + skb * 8;
    const unsigned short* pBl = Bl + (size_t)(n0 + srow) * K + skb * 8;
    unsigned lbase = __builtin_amdgcn_readfirstlane((unsigned)(wid * 1024));

    for (int k0 = 0; k0 < K; k0 += 32) {
        async16(pAh + k0, (char*)lAh + lbase);
        async16(pBh + k0, (char*)lBh + lbase);
        async16(pBh + (size_t)64 * K + k0, (char*)lBh + lbase + 4096);
        if (!isv) {
            async16(pAl + k0, (char*)lAl + lbase);
            async16(pBl + k0, (char*)lBl + lbase);
            async16(pBl + (size_t)64 * K + k0, (char*)lBl + lbase + 4096);
        }
        __syncthreads();

        short8 ah[2], al[2], bh[4], bl[4];
#pragma unroll
        for (int mt = 0; mt < 2; ++mt) {
            int row = mh + mt * 16 + (lane & 15);
            int s = ((lane >> 4) ^ ((row >> 1) & 3)) * 8;
            ah[mt] = *(const short8*)&lAh[row * 32 + s];
            if (!isv) al[mt] = *(const short8*)&lAl[row * 32 + s];
        }
#pragma unroll
        for (int nt = 0; nt < 4; ++nt) {
            int row = nh + nt * 16 + (lane & 15);
            int s = ((lane >> 4) ^ ((row >> 1) & 3)) * 8;
            bh[nt] = *(const short8*)&lBh[row * 32 + s];
            if (!isv) bl[nt] = *(const short8*)&lBl[row * 32 + s];
        }
        if (isv) {
#pragma unroll
            for (int mt = 0; mt < 2; ++mt)
#pragma unroll
                for (int nt = 0; nt < 4; ++nt)
                    acc[mt][nt] = __builtin_amdgcn_mfma_f32_16x16x32_bf16(ah[mt], bh[nt], acc[mt][nt], 0, 0, 0);
        } else {
#pragma unroll
            for (int mt = 0; mt < 2; ++mt)
#pragma unroll
                for (int nt = 0; nt < 4; ++nt) {
                    floatx4 a = acc[mt][nt];
                    a = __builtin_amdgcn_mfma_f32_16x16x32_bf16(al[mt], bh[nt], a, 0, 0, 0);
                    a = __builtin_amdgcn_mfma_f32_16x16x32_bf16(ah[mt], bl[nt], a, 0, 0, 0);
                    a = __builtin_amdgcn_mfma_f32_16x16x32_bf16(ah[mt], bh[nt], a, 0, 0, 0);
                    acc[mt][nt] = a;
                }
        }
        __syncthreads();
    }

    // ---- epilogue ----
    const int cb = n0 + nh;                      // wave's 64-col base
    if (!isv) {
        const bool isq = (cb < 1024);
        const float qsc = isq ? 0.125f : 1.0f;   // fold 1/sqrt(64) into q exactly
#pragma unroll
        for (int mt = 0; mt < 2; ++mt)
#pragma unroll
            for (int nt = 0; nt < 2; ++nt) {
                const int d32 = nt * 16 + (lane & 15);
#pragma unroll
                for (int rr = 0; rr < 4; ++rr) {
                    int row = m0 + mh + mt * 16 + (lane >> 4) * 4 + rr;
                    float lo = acc[mt][nt][rr], hi = acc[mt][nt + 2][rr];
                    float c = cosT[row * 32 + d32], s = sinT[row * 32 + d32];
                    float rlo = (lo * c - hi * s) * qsc;
                    float rhi = (hi * c + lo * s) * qsc;
                    unsigned short hlo = f2bf(rlo), hhi = f2bf(rhi);
                    unsigned short llo = f2bf(rlo - bf2f(hlo));
                    unsigned short lhi = f2bf(rhi - bf2f(hhi));
                    if (isq) {
                        size_t o = (size_t)row * DMODEL + cb + d32;
                        qhi[o] = hlo; qhi[o + 32] = hhi;
                        qlo[o] = llo; qlo[o + 32] = lhi;
                    } else {
                        int kvh = (cb - 1024) >> 6;
                        size_t o = ((size_t)kvh * SEQ + row) * DH + d32;
                        khi[o] = hlo; khi[o + 32] = hhi;
                        klo[o] = llo; klo[o + 32] = lhi;
                    }
                }
            }
    } else {
#pragma unroll
        for (int mt = 0; mt < 2; ++mt)
#pragma unroll
            for (int nt = 0; nt < 4; ++nt) {
                int vcol = cb + nt * 16 + (lane & 15) - 1280;
                int rbase = m0 + mh + mt * 16 + (lane >> 4) * 4;
#pragma unroll
                for (int rr = 0; rr < 4; ++rr)
                    vv[(size_t)(rbase + rr) * KV_D + vcol] = acc[mt][nt][rr];
            }
    }
}

// ---------------- Wo GEMM: 64x64 tile -> 512 blocks (2 blocks/CU) ----------------
__global__ __launch_bounds__(256, 4) void gemm_wo(const unsigned short* __restrict__ A,
                                                  const unsigned short* __restrict__ B,
                                                  float* __restrict__ C) {
    const int N = DMODEL, K = DMODEL;
    __shared__ unsigned short lAs[64 * 32];
    __shared__ unsigned short lBs[64 * 32];
    const int tid = threadIdx.x;
    const int lane = tid & 63;
    const int wid = tid >> 6;
    const int m0 = blockIdx.y * 64, n0 = blockIdx.x * 64;
    const int mq = (wid >> 1) * 32, nq = (wid & 1) * 32;

    floatx4 acc[2][2];
#pragma unroll
    for (int a = 0; a < 2; ++a)
#pragma unroll
        for (int b = 0; b < 2; ++b) acc[a][b] = (floatx4){0.f, 0.f, 0.f, 0.f};

    const int srow = tid >> 2;
    const int skb = (tid & 3) ^ ((tid >> 3) & 3);
    const unsigned short* Ag = A + (size_t)(m0 + srow) * K + skb * 8;
    const unsigned short* Bg = B + (size_t)(n0 + srow) * K + skb * 8;
    unsigned lbase = __builtin_amdgcn_readfirstlane((unsigned)(wid * 1024));

    for (int k0 = 0; k0 < K; k0 += 32) {
        async16(Ag + k0, (char*)lAs + lbase);
        async16(Bg + k0, (char*)lBs + lbase);
        __syncthreads();

        short8 af[2], bf[2];
#pragma unroll
        for (int mt = 0; mt < 2; ++mt) {
            int row = mq + mt * 16 + (lane & 15);
            int s = ((lane >> 4) ^ ((row >> 1) & 3)) * 8;
            af[mt] = *(const short8*)&lAs[row * 32 + s];
        }
#pragma unroll
        for (int nt = 0; nt < 2; ++nt) {
            int row = nq + nt * 16 + (lane & 15);
            int s = ((lane >> 4) ^ ((row >> 1) & 3)) * 8;
            bf[nt] = *(const short8*)&lBs[row * 32 + s];
        }
#pragma unroll
        for (int mt = 0; mt < 2; ++mt)
#pragma unroll
            for (int nt = 0; nt < 2; ++nt)
                acc[mt][nt] = __builtin_amdgcn_mfma_f32_16x16x32_bf16(af[mt], bf[nt], acc[mt][nt], 0, 0, 0);
        __syncthreads();
    }
#pragma unroll
    for (int mt = 0; mt < 2; ++mt)
#pragma unroll
        for (int nt = 0; nt < 2; ++nt) {
            int col = n0 + nq + nt * 16 + (lane & 15);
            int rbase = m0 + mq + mt * 16 + (lane >> 4) * 4;
#pragma unroll
            for (int rr = 0; rr < 4; ++rr)
                C[(size_t)(rbase + rr) * N + col] = acc[mt][nt][rr];
        }
}

// ---------------- AV fallback helper ----------------
__device__ __forceinline__ void av_group(float w, int jbase, const float* __restrict__ vb,
                                         float& acc) {
    unsigned long long mk = __ballot(w > 0.f);
    while (mk) {
        int l = __ffsll((unsigned long long)mk) - 1;
        mk &= mk - 1;
        float wj = __shfl(w, l, 64);
        acc += wj * vb[(size_t)(jbase + l * 4) * KV_D];
    }
}

// ---------------- phase-A score slice: strided j-blocks over a 1024-col chunk ----------------
__device__ __forceinline__ void score_chunk(const unsigned short* __restrict__ khi,
                                            const unsigned short* __restrict__ klo,
                                            float* __restrict__ S,
                                            const short8& ah0, const short8& ah1,
                                            const short8& al0, const short8& al1,
                                            int kvh, int w, int lane, int imax, int cbase) {
    const int koff = (lane >> 4) * 8;
#pragma unroll
    for (int n = 0; n < 4; ++n) {
        int jbi = cbase + w + n * 16;
        int jb = jbi * 16;
        if (jb <= imax) {
            size_t bidx = ((size_t)kvh * SEQ + jb + (lane & 15)) * DH + koff;
            short8 bh0 = *(const short8*)(khi + bidx);
            short8 bh1 = *(const short8*)(khi + bidx + 32);
            short8 bl0 = *(const short8*)(klo + bidx);
            short8 bl1 = *(const short8*)(klo + bidx + 32);
            floatx4 acc = (floatx4){0.f, 0.f, 0.f, 0.f};
            acc = __builtin_amdgcn_mfma_f32_16x16x32_bf16(al0, bh0, acc, 0, 0, 0);
            acc = __builtin_amdgcn_mfma_f32_16x16x32_bf16(al1, bh1, acc, 0, 0, 0);
            acc = __builtin_amdgcn_mfma_f32_16x16x32_bf16(ah0, bl0, acc, 0, 0, 0);
            acc = __builtin_amdgcn_mfma_f32_16x16x32_bf16(ah1, bl1, acc, 0, 0, 0);
            acc = __builtin_amdgcn_mfma_f32_16x16x32_bf16(ah0, bh0, acc, 0, 0, 0);
            acc = __builtin_amdgcn_mfma_f32_16x16x32_bf16(ah1, bh1, acc, 0, 0, 0);
            int col = (jb & 1023) + (lane & 15);
            int rbase = (lane >> 4) * 4;
#pragma unroll
            for (int rr = 0; rr < 4; ++rr)
                S[(size_t)(rbase + rr) * SROW + col] = acc[rr];   // q pre-scaled by 1/8
        }
    }
}

// ---------------- attention: block = (head, 16 q-rows), 16 waves, 2 blocks/CU ----------------
__global__ __launch_bounds__(1024, 8) void attn_block(const unsigned short* __restrict__ qhi,
                                                      const unsigned short* __restrict__ qlo,
                                                      const unsigned short* __restrict__ khi,
                                                      const unsigned short* __restrict__ klo,
                                                      const float* __restrict__ v,
                                                      unsigned short* __restrict__ outb) {
    extern __shared__ float S[];                 // [16][SROW] f32; own row reused as pair scratch
    const int lane = threadIdx.x & 63;
    const int w = threadIdx.x >> 6;              // 0..15
    const int t = 127 - blockIdx.x;              // longest tiles first
    const int h = blockIdx.y;
    const int kvh = h >> 2;
    const int m0 = t * 16;
    const int imax = m0 + 15;

    // A-fragments (q rows m0..m0+15)
    const int arow = m0 + (lane & 15);
    const int koff = (lane >> 4) * 8;
    size_t aidx = (size_t)arow * DMODEL + h * DH + koff;
    short8 ah0 = *(const short8*)(qhi + aidx);
    short8 ah1 = *(const short8*)(qhi + aidx + 32);
    short8 al0 = *(const short8*)(qlo + aidx);
    short8 al1 = *(const short8*)(qlo + aidx + 32);

    const int irow = m0 + w;
    const int cmax = (irow >> 8) + 1;
    float* Srow = S + (size_t)w * SROW;
    uint4 uv[8];
#pragma unroll
    for (int c = 0; c < 8; ++c) uv[c] = make_uint4(0u, 0u, 0u, 0u);

    // ---- chunk 0: cols [0,1024) ----
    score_chunk(khi, klo, S, ah0, ah1, al0, al1, kvh, w, lane, imax, 0);
    __syncthreads();
#pragma unroll
    for (int c = 0; c < 4; ++c) {
        if (c < cmax) {
            const int j0 = c * 256 + lane * 4;
            float4 f = *(const float4*)&Srow[j0];
            uv[c].x = (j0 + 0 <= irow) ? f2u(f.x) : 0u;
            uv[c].y = (j0 + 1 <= irow) ? f2u(f.y) : 0u;
            uv[c].z = (j0 + 2 <= irow) ? f2u(f.z) : 0u;
            uv[c].w = (j0 + 3 <= irow) ? f2u(f.w) : 0u;
        }
    }
    __syncthreads();

    // ---- chunk 1: cols [1024,2048) ----
    if (imax >= 1024) {
        score_chunk(khi, klo, S, ah0, ah1, al0, al1, kvh, w, lane, imax, 64);
    }
    __syncthreads();
#pragma unroll
    for (int c = 4; c < 8; ++c) {
        if (c < cmax) {
            const int j0 = (c - 4) * 256 + lane * 4;
            float4 f = *(const float4*)&Srow[j0];
            int jg = c * 256 + lane * 4;
            uv[c].x = (jg + 0 <= irow) ? f2u(f.x) : 0u;
            uv[c].y = (jg + 1 <= irow) ? f2u(f.y) : 0u;
            uv[c].z = (jg + 2 <= irow) ? f2u(f.z) : 0u;
            uv[c].w = (jg + 3 <= irow) ? f2u(f.w) : 0u;
        }
    }
    // no barrier needed: from here each wave only touches its OWN Srow.

    // per-lane max, then wave max (um) and wave min-of-lane-max (Lb)
    unsigned lmax = 0u;
#pragma unroll
    for (int c = 0; c < 8; ++c)
        lmax = max(lmax, max(max(uv[c].x, uv[c].y), max(uv[c].z, uv[c].w)));
    unsigned um = lmax, Lb = lmax;
#pragma unroll
    for (int o = 32; o > 0; o >>= 1) {
        um = max(um, (unsigned)__shfl_xor((int)um, o, 64));
        Lb = min(Lb, (unsigned)__shfl_xor((int)Lb, o, 64));
    }
    const float mf = u2f(um);

    // exact 64th-largest: max p with count(u >= p) >= 64.
    // Range is [Lb, um]: cnt(>=Lb) >= 64 (64 lane-maxima each >= Lb), cnt(>cand>um)=0.
    // Scalar guards skip ballot rounds when cand falls outside (Lb, um].
    unsigned p = 1u;
    if (irow >= TOPK) {
        unsigned diff = Lb ^ um;
        if (diff == 0u) {
            p = um;
        } else {
            int hb = 31 - __builtin_clz(diff);
            p = (hb >= 31) ? 0u : ((um >> (hb + 1)) << (hb + 1));
            for (int b = hb; b >= 0; --b) {
                unsigned cand = p | (1u << b);
                if (cand > um) continue;              // cnt = 0 -> reject, no ballots
                if (cand <= Lb) { p = cand; continue; } // cnt >= 64 -> accept, no ballots
                int cnt = 0;
#pragma unroll
                for (int c = 0; c < 8; ++c) {
                    if (c < cmax) {
                        cnt += __popcll(__ballot(uv[c].x >= cand));
                        cnt += __popcll(__ballot(uv[c].y >= cand));
                        cnt += __popcll(__ballot(uv[c].z >= cand));
                        cnt += __popcll(__ballot(uv[c].w >= cand));
                    }
                }
                if (cnt >= TOPK) p = cand;
            }
        }
    }

    // compact kept (w, j) pairs into own S row
    float2* pl = (float2*)Srow;
    const unsigned long long lmask = (lane == 0) ? 0ull : (~0ull >> (64 - lane));
    int base = 0;
#pragma unroll
    for (int c = 0; c < 8; ++c) {
        if (c < cmax) {
#pragma unroll
            for (int e = 0; e < 4; ++e) {
                unsigned u = (e == 0) ? uv[c].x : (e == 1) ? uv[c].y : (e == 2) ? uv[c].z : uv[c].w;
                bool kp = (u >= p);
                unsigned long long mk = __ballot(kp);
                if (kp) {
                    int pos = base + __popcll(mk & lmask);
                    if (pos < CAP)
                        pl[pos] = make_float2(__expf(u2f(u) - mf),
                                              __int_as_float(c * 256 + lane * 4 + e));
                }
                base += (int)__popcll(mk);
            }
        }
    }

    const float* vb = v + kvh * DH + lane;
    float acc = 0.f, den = 0.f;
    if (base <= CAP) {
        int l = 0;
        for (; l + 16 <= base; l += 16) {
            float2 pr[16];
            float vx[16];
#pragma unroll
            for (int u = 0; u < 16; ++u) pr[u] = pl[l + u];
#pragma unroll
            for (int u = 0; u < 16; ++u)
                vx[u] = vb[(size_t)__float_as_int(pr[u].y) * KV_D];
#pragma unroll
            for (int u = 0; u < 16; ++u) { den += pr[u].x; acc += pr[u].x * vx[u]; }
        }
        for (; l < base; ++l) {
            float2 pp = pl[l];
            den += pp.x;
            acc += pp.x * vb[(size_t)__float_as_int(pp.y) * KV_D];
        }
    } else {
        // fallback (massive ties): exact path from uv registers
        float lsum = 0.f;
#pragma unroll
        for (int c = 0; c < 8; ++c) {
            if (c < cmax) {
                float w0 = (uv[c].x >= p) ? __expf(u2f(uv[c].x) - mf) : 0.f;
                float w1 = (uv[c].y >= p) ? __expf(u2f(uv[c].y) - mf) : 0.f;
                float w2 = (uv[c].z >= p) ? __expf(u2f(uv[c].z) - mf) : 0.f;
                float w3 = (uv[c].w >= p) ? __expf(u2f(uv[c].w) - mf) : 0.f;
                lsum += (w0 + w1) + (w2 + w3);
                av_group(w0, c * 256 + 0, vb, acc);
                av_group(w1, c * 256 + 1, vb, acc);
                av_group(w2, c * 256 + 2, vb, acc);
                av_group(w3, c * 256 + 3, vb, acc);
            }
        }
        den = lsum;
#pragma unroll
        for (int o = 32; o > 0; o >>= 1) den += __shfl_xor(den, o, 64);
    }

    outb[(size_t)irow * DMODEL + h * DH + lane] = f2bf(acc / den);
}

extern "C" void kernel_launch(void* const* d_in, const int* in_sizes, int n_in,
                              void* d_out, int out_size, void* d_ws, size_t ws_size,
                              hipStream_t stream) {
    const float* x  = (const float*)d_in[0];
    const float* Wq = (const float*)d_in[1];
    const float* Wk = (const float*)d_in[2];
    const float* Wv = (const float*)d_in[3];
    const float* Wo = (const float*)d_in[4];
    float* out = (float*)d_out;

    float* ws = (float*)d_ws;
    float* vv   = ws;                               // 2048*256 f32
    float* cosT = vv + (size_t)SEQ * KV_D;          // 65536 f32
    float* sinT = cosT + SEQ * 32;                  // 65536 f32
    unsigned short* bfp = (unsigned short*)(sinT + SEQ * 32);
    unsigned short* xhi  = bfp;  bfp += (size_t)SEQ * DMODEL;      // 2M
    unsigned short* xlo  = bfp;  bfp += (size_t)SEQ * DMODEL;      // 2M
    unsigned short* wbhi = bfp;  bfp += (size_t)1536 * DMODEL;     // 1.5M
    unsigned short* wblo = bfp;  bfp += (size_t)1536 * DMODEL;     // 1.5M
    unsigned short* wob  = bfp;  bfp += (size_t)DMODEL * DMODEL;   // 1M
    unsigned short* qhi  = bfp;  bfp += (size_t)SEQ * DMODEL;      // 2M
    unsigned short* qlo  = bfp;  bfp += (size_t)SEQ * DMODEL;      // 2M
    unsigned short* khi  = bfp;  bfp += (size_t)KVH * SEQ * DH;    // 512K
    unsigned short* klo  = bfp;  bfp += (size_t)KVH * SEQ * DH;    // 512K
    unsigned short* attnb = xhi;   // xhi dead after QKV gemm

    dim3 blk(256);

    // converts + RoPE LUT (single launch)
    cvt_all<<<(1196032 + 255) / 256, blk, 0, stream>>>(x, Wq, Wk, Wv, Wo,
                                                       xhi, xlo, wbhi, wblo, wob,
                                                       cosT, sinT);

    // fused QKV projection + RoPE + layout (384 blocks)
    gemm_qkv<<<dim3(1536 / 128, SEQ / 64), blk, 0, stream>>>(xhi, xlo, wbhi, wblo,
                                                             cosT, sinT,
                                                             qhi, qlo, khi, klo, vv);

    // attention: 2 blocks/CU (S = 16 x 1028 floats = 65792 B)
    const int attn_lds = 16 * SROW * 4;
    hipFuncSetAttribute((const void*)attn_block,
                        hipFuncAttributeMaxDynamicSharedMemorySize, attn_lds);
    attn_block<<<dim3(SEQ / 16, QH), dim3(1024), attn_lds, stream>>>(qhi, qlo, khi, klo, vv, attnb);

    // output projection (512 blocks, 64x64 tiles)
    gemm_wo<<<dim3(DMODEL / 64, SEQ / 64), blk, 0, stream>>>(attnb, wob, out);
}

// Round 13
// 298.569 us; speedup vs baseline: 1.0370x; 1.0252x over previous
//
#include <hip/hip_runtime.h>
#include <hip/hip_bf16.h>
#include <math.h>

#define SEQ 2048
#define DMODEL 1024
#define QH 16
#define KVH 4
#define DH 64
#define TOPK 64
#define KV_D (KVH * DH)   // 256
#define CAP 128
#define SROW 1028         // padded S row stride (floats), half-seq chunk + 4

typedef __attribute__((ext_vector_type(8))) short short8;
typedef __attribute__((ext_vector_type(4))) float floatx4;

// ---------------- monotone float<->uint mapping ----------------
__device__ __forceinline__ unsigned f2u(float f) {
    unsigned u = __float_as_uint(f);
    return (u & 0x80000000u) ? ~u : (u | 0x80000000u);
}
__device__ __forceinline__ float u2f(unsigned u) {
    unsigned v = (u & 0x80000000u) ? (u & 0x7fffffffu) : ~u;
    return __uint_as_float(v);
}
__device__ __forceinline__ unsigned short f2bf(float x) {   // RNE f32->bf16
    unsigned u = __float_as_uint(x);
    return (unsigned short)((u + 0x7fffu + ((u >> 16) & 1u)) >> 16);
}
__device__ __forceinline__ float bf2f(unsigned short h) {
    return __uint_as_float((unsigned)h << 16);
}
__device__ __forceinline__ void split4(float4 f, ushort4& h, ushort4& l) {
    h.x = f2bf(f.x); l.x = f2bf(f.x - bf2f(h.x));
    h.y = f2bf(f.y); l.y = f2bf(f.y - bf2f(h.y));
    h.z = f2bf(f.z); l.z = f2bf(f.z - bf2f(h.z));
    h.w = f2bf(f.w); l.w = f2bf(f.w - bf2f(h.w));
}

// ---------------- fused converts + RoPE LUT in one launch ----------------
__global__ __launch_bounds__(256) void cvt_all(const float* __restrict__ x,
                                               const float* __restrict__ Wq,
                                               const float* __restrict__ Wk,
                                               const float* __restrict__ Wv,
                                               const float* __restrict__ Wo,
                                               unsigned short* __restrict__ xhi,
                                               unsigned short* __restrict__ xlo,
                                               unsigned short* __restrict__ wbhi,
                                               unsigned short* __restrict__ wblo,
                                               unsigned short* __restrict__ wo,
                                               float* __restrict__ cosT,
                                               float* __restrict__ sinT) {
    int idx = blockIdx.x * 256 + threadIdx.x;
    if (idx >= 1196032) return;
    float4 f;
    ushort4 h, l;
    if (idx < 524288) {                       // x split
        f = ((const float4*)x)[idx];
        split4(f, h, l);
        ((ushort4*)xhi)[idx] = h;
        ((ushort4*)xlo)[idx] = l;
    } else if (idx < 786432) {                // Wq -> wb rows 0..1023
        int s = idx - 524288;
        f = ((const float4*)Wq)[s];
        split4(f, h, l);
        ((ushort4*)wbhi)[s] = h;
        ((ushort4*)wblo)[s] = l;
    } else if (idx < 851968) {                // Wk -> wb rows 1024..1279
        int s = idx - 786432;
        f = ((const float4*)Wk)[s];
        split4(f, h, l);
        ((ushort4*)wbhi)[idx - 524288] = h;
        ((ushort4*)wblo)[idx - 524288] = l;
    } else if (idx < 917504) {                // Wv -> wb rows 1280..1535
        int s = idx - 851968;
        f = ((const float4*)Wv)[s];
        split4(f, h, l);
        ((ushort4*)wbhi)[idx - 524288] = h;
        ((ushort4*)wblo)[idx - 524288] = l;
    } else if (idx < 1179648) {               // Wo single bf16
        int s = idx - 917504;
        f = ((const float4*)Wo)[s];
        ushort4 o;
        o.x = f2bf(f.x); o.y = f2bf(f.y); o.z = f2bf(f.z); o.w = f2bf(f.w);
        ((ushort4*)wo)[s] = o;
    } else {                                   // RoPE cos/sin LUT, 4 entries/thread
        int s = idx - 1179648;                 // 0..16383
        int e0 = s * 4;
        float ft = (float)(e0 >> 5);
        int d0 = e0 & 31;
        float4 cw, sw;
#pragma unroll
        for (int k = 0; k < 4; ++k) {
            float inv = powf(10000.0f, -(float)(d0 + k) * (1.0f / 32.0f));
            float ss, cc;
            sincosf(ft * inv, &ss, &cc);
            ((float*)&cw)[k] = cc;
            ((float*)&sw)[k] = ss;
        }
        ((float4*)cosT)[s] = cw;
        ((float4*)sinT)[s] = sw;
    }
}

// ---------------- async 16B global->LDS ----------------
__device__ __forceinline__ void async16(const void* g, void* l) {
    __builtin_amdgcn_global_load_lds(
        (const __attribute__((address_space(1))) unsigned int*)g,
        (__attribute__((address_space(3))) unsigned int*)l, 16, 0, 0);
}

// ---------------- fused QKV GEMM (split bf16, ~f32) + RoPE epilogue ----------------
// 64x128 tile -> 384 blocks. Wave = 32 rows x 64 cols (rope (d,d+32) in-lane).
__global__ __launch_bounds__(256, 2) void gemm_qkv(const unsigned short* __restrict__ Ah,
                                                   const unsigned short* __restrict__ Al,
                                                   const unsigned short* __restrict__ Bh,
                                                   const unsigned short* __restrict__ Bl,
                                                   const float* __restrict__ cosT,
                                                   const float* __restrict__ sinT,
                                                   unsigned short* __restrict__ qhi,
                                                   unsigned short* __restrict__ qlo,
                                                   unsigned short* __restrict__ khi,
                                                   unsigned short* __restrict__ klo,
                                                   float* __restrict__ vv) {
    const int K = DMODEL;
    __shared__ unsigned short lAh[64 * 32];
    __shared__ unsigned short lAl[64 * 32];
    __shared__ unsigned short lBh[128 * 32];
    __shared__ unsigned short lBl[128 * 32];
    const int tid = threadIdx.x;
    const int lane = tid & 63;
    const int wid = tid >> 6;
    const int m0 = blockIdx.y * 64, n0 = blockIdx.x * 128;
    const int mh = (wid >> 1) * 32;             // wave row-half
    const int nh = (wid & 1) * 64;              // wave col-half (64 contiguous cols)
    const bool isv = (n0 >= 1280);

    floatx4 acc[2][4];
#pragma unroll
    for (int a = 0; a < 2; ++a)
#pragma unroll
        for (int b = 0; b < 4; ++b) acc[a][b] = (floatx4){0.f, 0.f, 0.f, 0.f};

    const int srow = tid >> 2;                  // 0..63
    const int skb = (tid & 3) ^ ((tid >> 3) & 3);
    const unsigned short* pAh = Ah + (size_t)(m0 + srow) * K + skb * 8;
    const unsigned short* pAl = Al + (size_t)(m0 + srow) * K + skb * 8;
    const unsigned short* pBh = Bh + (size_t)(n0 + srow) * K + skb * 8;
    const unsigned short* pBl = Bl + (size_t)(n0 + srow) * K + skb * 8;
    unsigned lbase = __builtin_amdgcn_readfirstlane((unsigned)(wid * 1024));

    for (int k0 = 0; k0 < K; k0 += 32) {
        async16(pAh + k0, (char*)lAh + lbase);
        async16(pBh + k0, (char*)lBh + lbase);
        async16(pBh + (size_t)64 * K + k0, (char*)lBh + lbase + 4096);
        if (!isv) {
            async16(pAl + k0, (char*)lAl + lbase);
            async16(pBl + k0, (char*)lBl + lbase);
            async16(pBl + (size_t)64 * K + k0, (char*)lBl + lbase + 4096);
        }
        __syncthreads();

        short8 ah[2], al[2], bh[4], bl[4];
#pragma unroll
        for (int mt = 0; mt < 2; ++mt) {
            int row = mh + mt * 16 + (lane & 15);
            int s = ((lane >> 4) ^ ((row >> 1) & 3)) * 8;
            ah[mt] = *(const short8*)&lAh[row * 32 + s];
            if (!isv) al[mt] = *(const short8*)&lAl[row * 32 + s];
        }
#pragma unroll
        for (int nt = 0; nt < 4; ++nt) {
            int row = nh + nt * 16 + (lane & 15);
            int s = ((lane >> 4) ^ ((row >> 1) & 3)) * 8;
            bh[nt] = *(const short8*)&lBh[row * 32 + s];
            if (!isv) bl[nt] = *(const short8*)&lBl[row * 32 + s];
        }
        if (isv) {
#pragma unroll
            for (int mt = 0; mt < 2; ++mt)
#pragma unroll
                for (int nt = 0; nt < 4; ++nt)
                    acc[mt][nt] = __builtin_amdgcn_mfma_f32_16x16x32_bf16(ah[mt], bh[nt], acc[mt][nt], 0, 0, 0);
        } else {
#pragma unroll
            for (int mt = 0; mt < 2; ++mt)
#pragma unroll
                for (int nt = 0; nt < 4; ++nt) {
                    floatx4 a = acc[mt][nt];
                    a = __builtin_amdgcn_mfma_f32_16x16x32_bf16(al[mt], bh[nt], a, 0, 0, 0);
                    a = __builtin_amdgcn_mfma_f32_16x16x32_bf16(ah[mt], bl[nt], a, 0, 0, 0);
                    a = __builtin_amdgcn_mfma_f32_16x16x32_bf16(ah[mt], bh[nt], a, 0, 0, 0);
                    acc[mt][nt] = a;
                }
        }
        __syncthreads();
    }

    // ---- epilogue ----
    const int cb = n0 + nh;                      // wave's 64-col base
    if (!isv) {
        const bool isq = (cb < 1024);
        const float qsc = isq ? 0.125f : 1.0f;   // fold 1/sqrt(64) into q exactly
#pragma unroll
        for (int mt = 0; mt < 2; ++mt)
#pragma unroll
            for (int nt = 0; nt < 2; ++nt) {
                const int d32 = nt * 16 + (lane & 15);
#pragma unroll
                for (int rr = 0; rr < 4; ++rr) {
                    int row = m0 + mh + mt * 16 + (lane >> 4) * 4 + rr;
                    float lo = acc[mt][nt][rr], hi = acc[mt][nt + 2][rr];
                    float c = cosT[row * 32 + d32], s = sinT[row * 32 + d32];
                    float rlo = (lo * c - hi * s) * qsc;
                    float rhi = (hi * c + lo * s) * qsc;
                    unsigned short hlo = f2bf(rlo), hhi = f2bf(rhi);
                    unsigned short llo = f2bf(rlo - bf2f(hlo));
                    unsigned short lhi = f2bf(rhi - bf2f(hhi));
                    if (isq) {
                        size_t o = (size_t)row * DMODEL + cb + d32;
                        qhi[o] = hlo; qhi[o + 32] = hhi;
                        qlo[o] = llo; qlo[o + 32] = lhi;
                    } else {
                        int kvh = (cb - 1024) >> 6;
                        size_t o = ((size_t)kvh * SEQ + row) * DH + d32;
                        khi[o] = hlo; khi[o + 32] = hhi;
                        klo[o] = llo; klo[o + 32] = lhi;
                    }
                }
            }
    } else {
#pragma unroll
        for (int mt = 0; mt < 2; ++mt)
#pragma unroll
            for (int nt = 0; nt < 4; ++nt) {
                int vcol = cb + nt * 16 + (lane & 15) - 1280;
                int rbase = m0 + mh + mt * 16 + (lane >> 4) * 4;
#pragma unroll
                for (int rr = 0; rr < 4; ++rr)
                    vv[(size_t)(rbase + rr) * KV_D + vcol] = acc[mt][nt][rr];
            }
    }
}

// ---------------- Wo GEMM: 64x128 tile -> 256 blocks ----------------
__global__ __launch_bounds__(256, 2) void gemm_wo(const unsigned short* __restrict__ A,
                                                  const unsigned short* __restrict__ B,
                                                  float* __restrict__ C) {
    const int N = DMODEL, K = DMODEL;
    __shared__ unsigned short lAs[64 * 32];
    __shared__ unsigned short lBs[128 * 32];
    const int tid = threadIdx.x;
    const int lane = tid & 63;
    const int wid = tid >> 6;
    const int m0 = blockIdx.y * 64, n0 = blockIdx.x * 128;

    floatx4 acc[4][2];
#pragma unroll
    for (int a = 0; a < 4; ++a)
#pragma unroll
        for (int b = 0; b < 2; ++b) acc[a][b] = (floatx4){0.f, 0.f, 0.f, 0.f};

    const int srow = tid >> 2;
    const int skb = (tid & 3) ^ ((tid >> 3) & 3);
    const unsigned short* Ag = A + (size_t)(m0 + srow) * K + skb * 8;
    const unsigned short* Bg = B + (size_t)(n0 + srow) * K + skb * 8;
    unsigned lbase = __builtin_amdgcn_readfirstlane((unsigned)(wid * 1024));

    for (int k0 = 0; k0 < K; k0 += 32) {
        async16(Ag + k0, (char*)lAs + lbase);
        async16(Bg + k0, (char*)lBs + lbase);
        async16(Bg + (size_t)64 * K + k0, (char*)lBs + lbase + 4096);
        __syncthreads();

        short8 af[4], bf[2];
#pragma unroll
        for (int mt = 0; mt < 4; ++mt) {
            int row = mt * 16 + (lane & 15);
            int s = ((lane >> 4) ^ ((row >> 1) & 3)) * 8;
            af[mt] = *(const short8*)&lAs[row * 32 + s];
        }
#pragma unroll
        for (int nt = 0; nt < 2; ++nt) {
            int row = wid * 32 + nt * 16 + (lane & 15);
            int s = ((lane >> 4) ^ ((row >> 1) & 3)) * 8;
            bf[nt] = *(const short8*)&lBs[row * 32 + s];
        }
#pragma unroll
        for (int mt = 0; mt < 4; ++mt)
#pragma unroll
            for (int nt = 0; nt < 2; ++nt)
                acc[mt][nt] = __builtin_amdgcn_mfma_f32_16x16x32_bf16(af[mt], bf[nt], acc[mt][nt], 0, 0, 0);
        __syncthreads();
    }
#pragma unroll
    for (int mt = 0; mt < 4; ++mt)
#pragma unroll
        for (int nt = 0; nt < 2; ++nt) {
            int col = n0 + wid * 32 + nt * 16 + (lane & 15);
            int rbase = m0 + mt * 16 + (lane >> 4) * 4;
#pragma unroll
            for (int rr = 0; rr < 4; ++rr)
                C[(size_t)(rbase + rr) * N + col] = acc[mt][nt][rr];
        }
}

// ---------------- AV fallback helper ----------------
__device__ __forceinline__ void av_group(float w, int jbase, const float* __restrict__ vb,
                                         float& acc) {
    unsigned long long mk = __ballot(w > 0.f);
    while (mk) {
        int l = __ffsll((unsigned long long)mk) - 1;
        mk &= mk - 1;
        float wj = __shfl(w, l, 64);
        acc += wj * vb[(size_t)(jbase + l * 4) * KV_D];
    }
}

// ---------------- phase-A score slice: strided j-blocks over a 1024-col chunk ----------------
__device__ __forceinline__ void score_chunk(const unsigned short* __restrict__ khi,
                                            const unsigned short* __restrict__ klo,
                                            float* __restrict__ S,
                                            const short8& ah0, const short8& ah1,
                                            const short8& al0, const short8& al1,
                                            int kvh, int w, int lane, int imax, int cbase) {
    const int koff = (lane >> 4) * 8;
#pragma unroll
    for (int n = 0; n < 4; ++n) {
        int jbi = cbase + w + n * 16;
        int jb = jbi * 16;
        if (jb <= imax) {
            size_t bidx = ((size_t)kvh * SEQ + jb + (lane & 15)) * DH + koff;
            short8 bh0 = *(const short8*)(khi + bidx);
            short8 bh1 = *(const short8*)(khi + bidx + 32);
            short8 bl0 = *(const short8*)(klo + bidx);
            short8 bl1 = *(const short8*)(klo + bidx + 32);
            floatx4 acc = (floatx4){0.f, 0.f, 0.f, 0.f};
            acc = __builtin_amdgcn_mfma_f32_16x16x32_bf16(al0, bh0, acc, 0, 0, 0);
            acc = __builtin_amdgcn_mfma_f32_16x16x32_bf16(al1, bh1, acc, 0, 0, 0);
            acc = __builtin_amdgcn_mfma_f32_16x16x32_bf16(ah0, bl0, acc, 0, 0, 0);
            acc = __builtin_amdgcn_mfma_f32_16x16x32_bf16(ah1, bl1, acc, 0, 0, 0);
            acc = __builtin_amdgcn_mfma_f32_16x16x32_bf16(ah0, bh0, acc, 0, 0, 0);
            acc = __builtin_amdgcn_mfma_f32_16x16x32_bf16(ah1, bh1, acc, 0, 0, 0);
            int col = (jb & 1023) + (lane & 15);
            int rbase = (lane >> 4) * 4;
#pragma unroll
            for (int rr = 0; rr < 4; ++rr)
                S[(size_t)(rbase + rr) * SROW + col] = acc[rr];   // q pre-scaled by 1/8
        }
    }
}

// ---------------- attention: block = (head, 16 q-rows), 16 waves, 2 blocks/CU ----------------
__global__ __launch_bounds__(1024, 8) void attn_block(const unsigned short* __restrict__ qhi,
                                                      const unsigned short* __restrict__ qlo,
                                                      const unsigned short* __restrict__ khi,
                                                      const unsigned short* __restrict__ klo,
                                                      const float* __restrict__ v,
                                                      unsigned short* __restrict__ outb) {
    extern __shared__ float S[];                 // [16][SROW] f32; own row reused as pair scratch
    const int lane = threadIdx.x & 63;
    const int w = threadIdx.x >> 6;              // 0..15
    const int t = 127 - blockIdx.x;              // longest tiles first
    const int h = blockIdx.y;
    const int kvh = h >> 2;
    const int m0 = t * 16;
    const int imax = m0 + 15;

    // A-fragments (q rows m0..m0+15)
    const int arow = m0 + (lane & 15);
    const int koff = (lane >> 4) * 8;
    size_t aidx = (size_t)arow * DMODEL + h * DH + koff;
    short8 ah0 = *(const short8*)(qhi + aidx);
    short8 ah1 = *(const short8*)(qhi + aidx + 32);
    short8 al0 = *(const short8*)(qlo + aidx);
    short8 al1 = *(const short8*)(qlo + aidx + 32);

    const int irow = m0 + w;
    const int cdiag = irow >> 8;                 // diagonal 256-col chunk
    float* Srow = S + (size_t)w * SROW;

    // scores held as floats; invalid slots = -INF
    float4 sc[8];
#pragma unroll
    for (int c = 0; c < 8; ++c)
        sc[c] = make_float4(-INFINITY, -INFINITY, -INFINITY, -INFINITY);

    // ---- chunk 0: cols [0,1024) ----
    score_chunk(khi, klo, S, ah0, ah1, al0, al1, kvh, w, lane, imax, 0);
    __syncthreads();
#pragma unroll
    for (int c = 0; c < 4; ++c) {
        if (c <= cdiag) {
            const int j0 = c * 256 + lane * 4;
            float4 f = *(const float4*)&Srow[j0];
            if (c < cdiag) {
                sc[c] = f;                        // fully below diagonal: no mask
            } else {
                sc[c].x = (j0 + 0 <= irow) ? f.x : -INFINITY;
                sc[c].y = (j0 + 1 <= irow) ? f.y : -INFINITY;
                sc[c].z = (j0 + 2 <= irow) ? f.z : -INFINITY;
                sc[c].w = (j0 + 3 <= irow) ? f.w : -INFINITY;
            }
        }
    }
    __syncthreads();

    // ---- chunk 1: cols [1024,2048) ----
    if (imax >= 1024) {
        score_chunk(khi, klo, S, ah0, ah1, al0, al1, kvh, w, lane, imax, 64);
    }
    __syncthreads();
#pragma unroll
    for (int c = 4; c < 8; ++c) {
        if (c <= cdiag) {
            const int j0 = (c - 4) * 256 + lane * 4;
            float4 f = *(const float4*)&Srow[j0];
            const int jg = c * 256 + lane * 4;
            if (c < cdiag) {
                sc[c] = f;
            } else {
                sc[c].x = (jg + 0 <= irow) ? f.x : -INFINITY;
                sc[c].y = (jg + 1 <= irow) ? f.y : -INFINITY;
                sc[c].z = (jg + 2 <= irow) ? f.z : -INFINITY;
                sc[c].w = (jg + 3 <= irow) ? f.w : -INFINITY;
            }
        }
    }
    // no barrier needed: from here each wave only touches its OWN Srow.

    // per-lane max, then wave max (um) and wave min-of-lane-max (Lb)
    float lmax = -INFINITY;
#pragma unroll
    for (int c = 0; c < 8; ++c)
        lmax = fmaxf(lmax, fmaxf(fmaxf(sc[c].x, sc[c].y), fmaxf(sc[c].z, sc[c].w)));
    float um = lmax, Lbf = lmax;
#pragma unroll
    for (int o = 32; o > 0; o >>= 1) {
        um = fmaxf(um, __shfl_xor(um, o, 64));
        Lbf = fminf(Lbf, __shfl_xor(Lbf, o, 64));
    }
    const float mf = um;

    // exact 64th-largest: max p with count(f >= u2f(p)) >= 64, float-domain compares.
    // All tested cands end >= 0x00800000 (u2f real float): cnt(>= -FLT_MAX) = nvalid >= 65
    // forces an accept by bit 23; -INF (masked) fails every compare.
    unsigned p = 0x00800000u;                    // keep-all: u2f = -FLT_MAX
    if (irow >= TOPK) {
        unsigned uum = f2u(um), uLb = f2u(Lbf);
        unsigned diff = uLb ^ uum;
        if (diff == 0u) {
            p = uum;
        } else {
            int hb = 31 - __builtin_clz(diff);
            p = (hb >= 31) ? 0u : ((uum >> (hb + 1)) << (hb + 1));
            for (int b = hb; b >= 0; --b) {
                unsigned cand = p | (1u << b);
                float cf = u2f(cand);
                int cnt = 0;
#pragma unroll
                for (int c = 0; c < 8; ++c) {
                    if (c <= cdiag) {
                        cnt += __popcll(__ballot(sc[c].x >= cf));
                        cnt += __popcll(__ballot(sc[c].y >= cf));
                        cnt += __popcll(__ballot(sc[c].z >= cf));
                        cnt += __popcll(__ballot(sc[c].w >= cf));
                    }
                }
                if (cnt >= TOPK) p = cand;
            }
            if (p < 0x00800000u) p = 0x00800000u;   // unreachable; safety
        }
    }
    const float thr = u2f(p);

    // compact kept (weight, v-byte-row-offset) pairs into own S row; den via reduce
    float2* pl = (float2*)Srow;
    const unsigned long long lmask = (lane == 0) ? 0ull : (~0ull >> (64 - lane));
    int base = 0;
    float lsum = 0.f;
#pragma unroll
    for (int c = 0; c < 8; ++c) {
        if (c <= cdiag) {
#pragma unroll
            for (int e = 0; e < 4; ++e) {
                float f = (e == 0) ? sc[c].x : (e == 1) ? sc[c].y : (e == 2) ? sc[c].z : sc[c].w;
                bool kp = (f >= thr);            // -INF always fails
                unsigned long long mk = __ballot(kp);
                if (kp) {
                    float wgt = __expf(f - mf);
                    lsum += wgt;
                    int pos = base + __popcll(mk & lmask);
                    if (pos < CAP)
                        pl[pos] = make_float2(wgt,
                                              __int_as_float((c * 256 + lane * 4 + e) << 8));
                }
                base += (int)__popcll(mk);
            }
        }
    }
    float den = lsum;
#pragma unroll
    for (int o = 32; o > 0; o >>= 1) den += __shfl_xor(den, o, 64);

    const float* vb = v + kvh * DH + lane;
    float acc = 0.f;
    if (base <= CAP) {
        int l = 0;
        for (; l + 16 <= base; l += 16) {
            float2 pr[16];
            float vx[16];
#pragma unroll
            for (int u = 0; u < 16; ++u) pr[u] = pl[l + u];
#pragma unroll
            for (int u = 0; u < 16; ++u)
                vx[u] = vb[__float_as_int(pr[u].y)];   // offset pre-scaled by KV_D
#pragma unroll
            for (int u = 0; u < 16; ++u) acc += pr[u].x * vx[u];
        }
        for (; l < base; ++l) {
            float2 pp = pl[l];
            acc += pp.x * vb[__float_as_int(pp.y)];
        }
    } else {
        // fallback (massive ties): exact path from sc registers (den already complete)
#pragma unroll
        for (int c = 0; c < 8; ++c) {
            if (c <= cdiag) {
                float w0 = (sc[c].x >= thr) ? __expf(sc[c].x - mf) : 0.f;
                float w1 = (sc[c].y >= thr) ? __expf(sc[c].y - mf) : 0.f;
                float w2 = (sc[c].z >= thr) ? __expf(sc[c].z - mf) : 0.f;
                float w3 = (sc[c].w >= thr) ? __expf(sc[c].w - mf) : 0.f;
                av_group(w0, c * 256 + 0, vb, acc);
                av_group(w1, c * 256 + 1, vb, acc);
                av_group(w2, c * 256 + 2, vb, acc);
                av_group(w3, c * 256 + 3, vb, acc);
            }
        }
    }

    outb[(size_t)irow * DMODEL + h * DH + lane] = f2bf(acc / den);
}

extern "C" void kernel_launch(void* const* d_in, const int* in_sizes, int n_in,
                              void* d_out, int out_size, void* d_ws, size_t ws_size,
                              hipStream_t stream) {
    const float* x  = (const float*)d_in[0];
    const float* Wq = (const float*)d_in[1];
    const float* Wk = (const float*)d_in[2];
    const float* Wv = (const float*)d_in[3];
    const float* Wo = (const float*)d_in[4];
    float* out = (float*)d_out;

    float* ws = (float*)d_ws;
    float* vv   = ws;                               // 2048*256 f32
    float* cosT = vv + (size_t)SEQ * KV_D;          // 65536 f32
    float* sinT = cosT + SEQ * 32;                  // 65536 f32
    unsigned short* bfp = (unsigned short*)(sinT + SEQ * 32);
    unsigned short* xhi  = bfp;  bfp += (size_t)SEQ * DMODEL;      // 2M
    unsigned short* xlo  = bfp;  bfp += (size_t)SEQ * DMODEL;      // 2M
    unsigned short* wbhi = bfp;  bfp += (size_t)1536 * DMODEL;     // 1.5M
    unsigned short* wblo = bfp;  bfp += (size_t)1536 * DMODEL;     // 1.5M
    unsigned short* wob  = bfp;  bfp += (size_t)DMODEL * DMODEL;   // 1M
    unsigned short* qhi  = bfp;  bfp += (size_t)SEQ * DMODEL;      // 2M
    unsigned short* qlo  = bfp;  bfp += (size_t)SEQ * DMODEL;      // 2M
    unsigned short* khi  = bfp;  bfp += (size_t)KVH * SEQ * DH;    // 512K
    unsigned short* klo  = bfp;  bfp += (size_t)KVH * SEQ * DH;    // 512K
    unsigned short* attnb = xhi;   // xhi dead after QKV gemm

    dim3 blk(256);

    // converts + RoPE LUT (single launch)
    cvt_all<<<(1196032 + 255) / 256, blk, 0, stream>>>(x, Wq, Wk, Wv, Wo,
                                                       xhi, xlo, wbhi, wblo, wob,
                                                       cosT, sinT);

    // fused QKV projection + RoPE + layout (384 blocks)
    gemm_qkv<<<dim3(1536 / 128, SEQ / 64), blk, 0, stream>>>(xhi, xlo, wbhi, wblo,
                                                             cosT, sinT,
                                                             qhi, qlo, khi, klo, vv);

    // attention: 2 blocks/CU (S = 16 x 1028 floats = 65792 B)
    const int attn_lds = 16 * SROW * 4;
    hipFuncSetAttribute((const void*)attn_block,
                        hipFuncAttributeMaxDynamicSharedMemorySize, attn_lds);
    attn_block<<<dim3(SEQ / 16, QH), dim3(1024), attn_lds, stream>>>(qhi, qlo, khi, klo, vv, attnb);

    // output projection (256 blocks, 64x128 tiles)
    gemm_wo<<<dim3(DMODEL / 128, SEQ / 64), blk, 0, stream>>>(attnb, wob, out);
}